// Round 6
// baseline (910.340 us; speedup 1.0000x reference)
//
#include <hip/hip_runtime.h>
#include <cstdint>
#include <cstddef>

typedef _Float16 f16;
typedef _Float16 f16x8 __attribute__((ext_vector_type(8)));
typedef _Float16 f16x4 __attribute__((ext_vector_type(4)));
typedef float f32x4 __attribute__((ext_vector_type(4)));

#define DEVI __device__ __forceinline__

// ---------------- problem sizes ----------------
constexpr int T_ = 256;
constexpr int BATCH = 512;
constexpr int M_ = BATCH * T_;   // 131072 tokens
constexpr int KE_ = 320;         // layer-1 K (300 padded to 320)
constexpr int K2_ = 256;         // layer-2 K

// ---------------- ws layout (bytes, 16B aligned) ----------------
constexpr size_t OFF_EMB16 = 0;                                     // [10000][320] f16
constexpr size_t OFF_WIH1  = OFF_EMB16 + (size_t)10000 * KE_ * 2;   // [1024][320] f16 (tile-permuted)
constexpr size_t OFF_WIH2  = OFF_WIH1 + (size_t)1024 * KE_ * 2;     // [1024][256] f16
constexpr size_t OFF_WHH   = OFF_WIH2 + (size_t)1024 * K2_ * 2;     // [4 ld][8w][64lane][16frag][8] f16
constexpr size_t OFF_B1    = OFF_WHH + (size_t)4 * 65536 * 2;       // [1024] f32 permuted bias
constexpr size_t OFF_B2    = OFF_B1 + 4096;                         // [1024] f32
constexpr size_t OFF_W1T   = OFF_B2 + 4096;                         // [512][512] f32 (transposed)
constexpr size_t OFF_W2T   = OFF_W1T + (size_t)512 * 512 * 4;
constexpr size_t OFF_POOL  = OFF_W2T + (size_t)512 * 512 * 4;       // [512][512] f32 (avg|max)
constexpr size_t OFF_XG1   = OFF_POOL + (size_t)512 * 512 * 4;      // [10240][1024] f16 token table (21MB)
constexpr size_t OFF_H1    = OFF_XG1 + (size_t)10240 * 1024 * 2;    // [131072][256] f16 (67MB)
constexpr size_t OFF_XG2   = OFF_H1 + (size_t)M_ * 256 * 2;         // [M_/G][1024] f16 chunk
constexpr size_t XG2_FULL  = (size_t)M_ * 1024 * 2;                 // 268MB full

DEVI void gload_lds16(const void* g, void* l) {
  __builtin_amdgcn_global_load_lds((const __attribute__((address_space(1))) void*)g,
                                   (__attribute__((address_space(3))) void*)l, 16, 0, 0);
}
DEVI float sigm(float x)  { return __builtin_amdgcn_rcpf(1.f + __expf(-x)); }
DEVI float tanh_(float x) { return 1.f - 2.f * __builtin_amdgcn_rcpf(1.f + __expf(2.f * x)); }

// xg col layout: col = dir*512 + unit*4 + gate   (gate contiguous, unit next)
// GEMM N-tile nt = dir*4 + ug; within tile r = wn*64 + j*16 + c0 -> gate=j, unit=ug*32+wn*16+c0
// B-perm row p = nt*128 + r -> orig W row = gate*128 + unit (per dir)
DEVI int borow(int p) {
  int r = p & 127;
  int ug = (p >> 7) & 3;
  int wn = r >> 6, j = (r >> 4) & 3, c0 = r & 15;
  return j * 128 + ug * 32 + wn * 16 + c0;
}

// ---------------- prep: fp16 conversion, permutation, fragment pre-arrangement ----------------
__global__ void prep_kernel(
    const float* __restrict__ emb,
    const float* __restrict__ wih1f, const float* __restrict__ whh1f,
    const float* __restrict__ bih1f, const float* __restrict__ bhh1f,
    const float* __restrict__ wih1b, const float* __restrict__ whh1b,
    const float* __restrict__ bih1b, const float* __restrict__ bhh1b,
    const float* __restrict__ wih2f, const float* __restrict__ whh2f,
    const float* __restrict__ bih2f, const float* __restrict__ bhh2f,
    const float* __restrict__ wih2b, const float* __restrict__ whh2b,
    const float* __restrict__ bih2b, const float* __restrict__ bhh2b,
    const float* __restrict__ w1, const float* __restrict__ w2,
    char* __restrict__ ws)
{
  f16* emb16   = (f16*)(ws + OFF_EMB16);
  f16* wih1p   = (f16*)(ws + OFF_WIH1);
  f16* wih2p   = (f16*)(ws + OFF_WIH2);
  f16* whhp    = (f16*)(ws + OFF_WHH);
  float* b1p   = (float*)(ws + OFF_B1);
  float* b2p   = (float*)(ws + OFF_B2);
  float* w1t   = (float*)(ws + OFF_W1T);
  float* w2t   = (float*)(ws + OFF_W2T);
  const int64_t stride = (int64_t)gridDim.x * blockDim.x;
  const int64_t t0 = (int64_t)blockIdx.x * blockDim.x + threadIdx.x;

  for (int64_t i = t0; i < (int64_t)10000 * 320; i += stride) {
    int r = (int)(i / 320), c = (int)(i % 320);
    emb16[i] = (c < 300) ? (f16)emb[r * 300 + c] : (f16)0.f;
  }
  for (int64_t i = t0; i < 1024 * 320; i += stride) {
    int p = (int)(i / 320), k = (int)(i % 320);
    int dir = p >> 9; int orig = borow(p & 511);
    const float* src = dir ? wih1b : wih1f;
    wih1p[i] = (k < 300) ? (f16)src[orig * 300 + k] : (f16)0.f;
  }
  for (int64_t i = t0; i < 1024 * 256; i += stride) {
    int p = (int)(i / 256), k = (int)(i % 256);
    int dir = p >> 9; int orig = borow(p & 511);
    const float* src = dir ? wih2b : wih2f;
    wih2p[i] = (f16)src[orig * 256 + k];
  }
  // W_hh recur B-frags: [(ld*8 + w)*64 + lane][frag f=g*4+kk][e]
  //   N-row = g*128 + w*16 + (lane&15);  k = kk*32 + (lane>>4)*8 + e
  for (int64_t i = t0; i < (int64_t)4 * 65536; i += stride) {
    int ld = (int)(i >> 16);              // layer*2 + dir
    int rem = (int)(i & 65535);
    int rec = rem >> 7;                    // w*64 + lane
    int w_ = rec >> 6, lane_ = rec & 63;
    int fe = rem & 127; int f_ = fe >> 3, e_ = fe & 7;
    int g_ = f_ >> 2, kk_ = f_ & 3;
    int n = g_ * 128 + w_ * 16 + (lane_ & 15);
    int k = kk_ * 32 + (lane_ >> 4) * 8 + e_;
    const float* src = (ld == 0) ? whh1f : (ld == 1) ? whh1b : (ld == 2) ? whh2f : whh2b;
    whhp[i] = (f16)src[n * 128 + k];
  }
  for (int64_t i = t0; i < 1024; i += stride) {
    int dir = (int)(i >> 9); int orig = borow((int)(i & 511));
    b1p[i] = dir ? (bih1b[orig] + bhh1b[orig]) : (bih1f[orig] + bhh1f[orig]);
    b2p[i] = dir ? (bih2b[orig] + bhh2b[orig]) : (bih2f[orig] + bhh2f[orig]);
  }
  for (int64_t i = t0; i < 512 * 512; i += stride) {
    int k = (int)(i >> 9), j = (int)(i & 511);
    w1t[i] = w1[j * 512 + k];
    w2t[i] = w2[j * 512 + k];
  }
}

// ---------------- input-gate GEMM: packed-layout xg, double-buffered LDS ----------------
// A rows linear (chunk-local / table rows). 128x128 tile, BK=64, 4 waves.
template<int KT>
__global__ __launch_bounds__(256, 2) void gemm_xg(
    const f16* __restrict__ Asrc, const f16* __restrict__ Bw,
    const float* __restrict__ bias, f16* __restrict__ xg)
{
  __shared__ __align__(16) f16 lA[2][8192];
  __shared__ __align__(16) f16 lB[2][8192];
  const int tid = threadIdx.x;
  const int w = tid >> 6, lane = tid & 63;
  const int mt = blockIdx.x >> 3, nt = blockIdx.x & 7;
  const int wm = w & 1, wn = w >> 1;
  const int l3 = lane >> 3, l7 = lane & 7;
  const int c0 = lane & 15, kg = lane >> 4;
  const int swz = l7 ^ l3;

  const f16* asrc[4];
  const f16* bsrc[4];
#pragma unroll
  for (int c = 0; c < 4; ++c) {
    int r = c * 32 + w * 8 + l3;
    asrc[c] = Asrc + (size_t)(mt * 128 + r) * (KT * 64) + swz * 8;
    bsrc[c] = Bw + (size_t)(nt * 128 + r) * (KT * 64) + swz * 8;
  }
  auto stage = [&](int kk, int d) {
#pragma unroll
    for (int c = 0; c < 4; ++c)
      gload_lds16(asrc[c] + kk * 64, &lA[d][(c * 256 + w * 64) * 8]);
#pragma unroll
    for (int c = 0; c < 4; ++c)
      gload_lds16(bsrc[c] + kk * 64, &lB[d][(c * 256 + w * 64) * 8]);
  };

  f32x4 acc[4][4] = {};
  stage(0, 0);
  for (int kk = 0; kk < KT; ++kk) {
    const int d = kk & 1;
    if (kk + 1 < KT) {
      stage(kk + 1, d ^ 1);
      asm volatile("s_waitcnt vmcnt(8)" ::: "memory");   // current tile landed, next in flight
    } else {
      asm volatile("s_waitcnt vmcnt(0)" ::: "memory");
    }
    __builtin_amdgcn_s_barrier();

    f16x8 af[2][4], bf[2][4];
#pragma unroll
    for (int s = 0; s < 2; ++s)
#pragma unroll
      for (int i = 0; i < 4; ++i) {
        int ra = wm * 64 + i * 16 + c0;
        int rb = wn * 64 + i * 16 + c0;
        int u = (s * 4 + kg) ^ l7;
        af[s][i] = *(const f16x8*)&lA[d][ra * 64 + u * 8];
        bf[s][i] = *(const f16x8*)&lB[d][rb * 64 + u * 8];
      }
#pragma unroll
    for (int s = 0; s < 2; ++s)
#pragma unroll
      for (int i = 0; i < 4; ++i)
#pragma unroll
        for (int j = 0; j < 4; ++j)
          acc[i][j] = __builtin_amdgcn_mfma_f32_16x16x32_f16(af[s][i], bf[s][j], acc[i][j], 0, 0, 0);
    asm volatile("s_waitcnt lgkmcnt(0)" ::: "memory");
    __builtin_amdgcn_s_barrier();
  }

  const int dir = nt >> 2, ug = nt & 3;
  const int unit = ug * 32 + wn * 16 + c0;
  float bj[4];
#pragma unroll
  for (int j = 0; j < 4; ++j) bj[j] = bias[nt * 128 + wn * 64 + j * 16 + c0];
#pragma unroll
  for (int i = 0; i < 4; ++i)
#pragma unroll
    for (int r = 0; r < 4; ++r) {
      int m = mt * 128 + wm * 64 + i * 16 + kg * 4 + r;
      f16x4 v = { (f16)(acc[i][0][r] + bj[0]), (f16)(acc[i][1][r] + bj[1]),
                  (f16)(acc[i][2][r] + bj[2]), (f16)(acc[i][3][r] + bj[3]) };
      *(f16x4*)&xg[(size_t)m * 1024 + dir * 512 + unit * 4] = v;
    }
}

// ---------------- LSTM recurrence v5: ROWS-per-block (TLP), dir-per-block, 4 waves ----------------
// block = (dir, ROWS-batch group); wave sp owns units [sp*32, sp*32+32) as 2 sub-slices.
// ROWS in {1,2,4}: rows live at MFMA M-rows j*4; lanes kg>=ROWS are clamped+predicated off.
// L1 (!IS_L2): xg = token table [10240][1024], gathered by token id (LLC-resident).
template<int IS_L2, int ROWS>
__global__ __launch_bounds__(256, 2) void recur_kernel(
    const f16* __restrict__ xg, const int* __restrict__ xtok,
    const f16* __restrict__ whh2, f16* __restrict__ h1,
    float* __restrict__ pool, int b0, int nblk)
{
  const int tid = threadIdx.x;
  const int sp = tid >> 6, lane = tid & 63;
  const int dir = blockIdx.x / nblk, ci = blockIdx.x % nblk;
  const int c0 = lane & 15, kg = lane >> 4;
  const int kgc = (kg < ROWS) ? kg : (ROWS - 1);       // clamped (OOB-safe addressing)
  const bool wr = (kg < ROWS);                          // store predicate

  __shared__ __align__(16) f16 hbuf[2][4][144];

  f16x8 Wf[2][16];                                   // 128 VGPR of W_hh B-frags
#pragma unroll
  for (int s = 0; s < 2; ++s) {
    const f16x8* wp = (const f16x8*)(whh2 + (size_t)dir * 65536 +
                                     (size_t)((sp * 2 + s) * 64 + lane) * 128);
#pragma unroll
    for (int f = 0; f < 16; ++f) Wf[s][f] = wp[f];
  }
  for (int i = tid; i < 2 * 4 * 144; i += 256) (&hbuf[0][0][0])[i] = (f16)0.f;
  __syncthreads();

  const int u0 = sp * 32 + c0, u1 = u0 + 16;
  const int brow = ci * ROWS + kgc;                  // chunk-local batch row (clamped)
  const int gb = b0 + brow;                          // global batch row
  const f16* xgu0 = xg + dir * 512 + u0 * 4;
  const f16* xgu1 = xg + dir * 512 + u1 * 4;
  const int* xr = nullptr;
  if constexpr (!IS_L2) xr = xtok + (size_t)gb * 256;

  auto tAt = [&](int step) { int s = step < 256 ? step : 255; return dir ? 255 - s : s; };

  float cst[2] = {0.f, 0.f}, psum[2] = {0.f, 0.f}, pmax[2] = {-1e30f, -1e30f};

  f16x4 xa[2], xb[2];
  int tok1 = 0;
  if constexpr (!IS_L2) {
    const int tok0 = xr[tAt(0)];
    xa[0] = *(const f16x4*)(xgu0 + (size_t)tok0 * 1024);
    xa[1] = *(const f16x4*)(xgu1 + (size_t)tok0 * 1024);
    tok1 = xr[tAt(1)];
  } else {
    const size_t m0 = ((size_t)brow * 256 + tAt(0)) * 1024;
    xa[0] = *(const f16x4*)(xgu0 + m0);
    xa[1] = *(const f16x4*)(xgu1 + m0);
  }

  auto body = [&](int step, int p, f16x4* cur, f16x4* nxt) {
    const int t = tAt(step);
    if constexpr (!IS_L2) {
      const size_t mn = (size_t)tok1 * 1024;          // token loaded last iter
      nxt[0] = *(const f16x4*)(xgu0 + mn);
      nxt[1] = *(const f16x4*)(xgu1 + mn);
      tok1 = xr[tAt(step + 2)];                       // token for step+2
    } else {
      const size_t mn = ((size_t)brow * 256 + tAt(step + 1)) * 1024;
      nxt[0] = *(const f16x4*)(xgu0 + mn);
      nxt[1] = *(const f16x4*)(xgu1 + mn);
    }

    f16x8 a[4];
#pragma unroll
    for (int q = 0; q < 4; ++q)
      a[q] = *(const f16x8*)&hbuf[p][c0 >> 2][q * 32 + kg * 8];

    f32x4 acc[2][4] = {};
    __builtin_amdgcn_s_setprio(1);
#pragma unroll
    for (int s = 0; s < 2; ++s)
#pragma unroll
      for (int g = 0; g < 4; ++g)
#pragma unroll
        for (int q = 0; q < 4; ++q)
          acc[s][g] = __builtin_amdgcn_mfma_f32_16x16x32_f16(a[q], Wf[s][g * 4 + q], acc[s][g], 0, 0, 0);
    __builtin_amdgcn_s_setprio(0);

#pragma unroll
    for (int s = 0; s < 2; ++s) {
      const float gi = acc[s][0][0] + (float)cur[s][0];
      const float gf = acc[s][1][0] + (float)cur[s][1];
      const float gG = acc[s][2][0] + (float)cur[s][2];
      const float go = acc[s][3][0] + (float)cur[s][3];
      const float si = sigm(gi), sf = sigm(gf), so = sigm(go);
      const float cn = sf * cst[s] + si * tanh_(gG);
      cst[s] = cn;
      const float hv = so * tanh_(cn);
      if (wr) {
        hbuf[p ^ 1][kg][s ? u1 : u0] = (f16)hv;
        if constexpr (!IS_L2)
          h1[((size_t)gb * 256 + t) * 256 + dir * 128 + (s ? u1 : u0)] = (f16)hv;
      }
      if constexpr (IS_L2) {
        psum[s] += hv;
        pmax[s] = fmaxf(pmax[s], hv);
      }
    }
    asm volatile("s_waitcnt lgkmcnt(0)" ::: "memory"); // hbuf reads+writes done
    __builtin_amdgcn_s_barrier();                      // single barrier per step
  };

#pragma unroll 1
  for (int s2 = 0; s2 < 128; ++s2) {                   // static reg double-buffer
    body(2 * s2, 0, xa, xb);
    body(2 * s2 + 1, 1, xb, xa);
  }

  if constexpr (IS_L2) {
    if (wr) {
      pool[(size_t)gb * 512 + dir * 128 + u0] = psum[0] * (1.f / 256.f);
      pool[(size_t)gb * 512 + dir * 128 + u1] = psum[1] * (1.f / 256.f);
      pool[(size_t)gb * 512 + 256 + dir * 128 + u0] = pmax[0];
      pool[(size_t)gb * 512 + 256 + dir * 128 + u1] = pmax[1];
    }
  }
}

// ---------------- head: dense(512x512)x2 + residual + out/aux projections ----------------
__global__ __launch_bounds__(256) void head_kernel(
    const float* __restrict__ pool,
    const float* __restrict__ w1t, const float* __restrict__ w2t,
    const float* __restrict__ b1, const float* __restrict__ b2,
    const float* __restrict__ wout, const float* __restrict__ bout,
    const float* __restrict__ waux, const float* __restrict__ baux,
    float* __restrict__ out)
{
  __shared__ float hc[4][512];
  __shared__ float hid[4][512];
  const int tid = threadIdx.x;
  const int rb = blockIdx.x * 4;
  for (int i = tid; i < 2048; i += 256) hc[i >> 9][i & 511] = pool[(size_t)rb * 512 + i];
  __syncthreads();

  float acc1[2][4] = {}, acc2[2][4] = {};
  for (int k = 0; k < 512; ++k) {
    float w1a = w1t[k * 512 + tid], w1b = w1t[k * 512 + tid + 256];
    float w2a = w2t[k * 512 + tid], w2b = w2t[k * 512 + tid + 256];
#pragma unroll
    for (int r = 0; r < 4; ++r) {
      float h = hc[r][k];
      acc1[0][r] += w1a * h; acc1[1][r] += w1b * h;
      acc2[0][r] += w2a * h; acc2[1][r] += w2b * h;
    }
  }
#pragma unroll
  for (int r = 0; r < 4; ++r) {
    hid[r][tid] = fmaxf(acc1[0][r] + b1[tid], 0.f) + hc[r][tid] + fmaxf(acc2[0][r] + b2[tid], 0.f);
    hid[r][tid + 256] = fmaxf(acc1[1][r] + b1[tid + 256], 0.f) + hc[r][tid + 256]
                      + fmaxf(acc2[1][r] + b2[tid + 256], 0.f);
  }
  __syncthreads();

  const int wv = tid >> 6, lane = tid & 63;
  for (int o = 0; o < 7; ++o) {
    const float* wrow = (o == 0) ? wout : (waux + (size_t)(o - 1) * 512);
    float s = 0.f;
#pragma unroll
    for (int m = 0; m < 8; ++m) s += hid[wv][lane + 64 * m] * wrow[lane + 64 * m];
#pragma unroll
    for (int off = 32; off >= 1; off >>= 1) s += __shfl_xor(s, off, 64);
    if (lane == 0) out[(size_t)(rb + wv) * 7 + o] = s + ((o == 0) ? bout[0] : baux[o - 1]);
  }
}

// ---------------- launcher ----------------
extern "C" void kernel_launch(void* const* d_in, const int* in_sizes, int n_in,
                              void* d_out, int out_size, void* d_ws, size_t ws_size,
                              hipStream_t stream) {
  const int*   x     = (const int*)d_in[0];
  const float* emb   = (const float*)d_in[1];
  const float* wih1f = (const float*)d_in[2];
  const float* whh1f = (const float*)d_in[3];
  const float* bih1f = (const float*)d_in[4];
  const float* bhh1f = (const float*)d_in[5];
  const float* wih1b = (const float*)d_in[6];
  const float* whh1b = (const float*)d_in[7];
  const float* bih1b = (const float*)d_in[8];
  const float* bhh1b = (const float*)d_in[9];
  const float* wih2f = (const float*)d_in[10];
  const float* whh2f = (const float*)d_in[11];
  const float* bih2f = (const float*)d_in[12];
  const float* bhh2f = (const float*)d_in[13];
  const float* wih2b = (const float*)d_in[14];
  const float* whh2b = (const float*)d_in[15];
  const float* bih2b = (const float*)d_in[16];
  const float* bhh2b = (const float*)d_in[17];
  const float* w1    = (const float*)d_in[18];
  const float* b1    = (const float*)d_in[19];
  const float* w2    = (const float*)d_in[20];
  const float* b2    = (const float*)d_in[21];
  const float* wout  = (const float*)d_in[22];
  const float* bout  = (const float*)d_in[23];
  const float* waux  = (const float*)d_in[24];
  const float* baux  = (const float*)d_in[25];

  char* ws = (char*)d_ws;
  f16* emb16 = (f16*)(ws + OFF_EMB16);
  f16* wih1p = (f16*)(ws + OFF_WIH1);
  f16* wih2p = (f16*)(ws + OFF_WIH2);
  f16* whhp  = (f16*)(ws + OFF_WHH);
  float* b1p = (float*)(ws + OFF_B1);
  float* b2p = (float*)(ws + OFF_B2);
  float* w1t = (float*)(ws + OFF_W1T);
  float* w2t = (float*)(ws + OFF_W2T);
  float* pool = (float*)(ws + OFF_POOL);
  f16* xg1t  = (f16*)(ws + OFF_XG1);
  f16* h1f   = (f16*)(ws + OFF_H1);
  f16* xg2c  = (f16*)(ws + OFF_XG2);

  // chunk factor G for the layer-2 xg buffer only (pure function of ws_size)
  int G = 1;
  while (G < 32 && OFF_XG2 + XG2_FULL / (size_t)G > ws_size) G <<= 1;
  const int Bc = BATCH / G;

  prep_kernel<<<4096, 256, 0, stream>>>(emb,
      wih1f, whh1f, bih1f, bhh1f, wih1b, whh1b, bih1b, bhh1b,
      wih2f, whh2f, bih2f, bhh2f, wih2b, whh2b, bih2b, bhh2b,
      w1, w2, ws);

  // layer-1 gate table over the 10000-token vocabulary (80 M-tiles of 128)
  gemm_xg<5><<<80 * 8, 256, 0, stream>>>(emb16, wih1p, b1p, xg1t);

  // layer-1 recurrence: full batch, ROWS=2 -> 512 blocks (2 blocks/CU)
  recur_kernel<0, 2><<<2 * 256, 256, 0, stream>>>(xg1t, x, whhp, h1f, nullptr, 0, 256);

  // layer-2: chunked input GEMM + recurrence (ROWS sized so grid ~512)
  for (int g = 0; g < G; ++g) {
    const int b0 = g * Bc;
    gemm_xg<4><<<(Bc * 2) * 8, 256, 0, stream>>>(h1f + (size_t)b0 * 65536, wih2p, b2p, xg2c);
    if (Bc >= 512) {
      recur_kernel<1, 2><<<2 * (Bc / 2), 256, 0, stream>>>(xg2c, nullptr, whhp + 2 * 65536,
                                                           nullptr, pool, b0, Bc / 2);
    } else {
      recur_kernel<1, 1><<<2 * Bc, 256, 0, stream>>>(xg2c, nullptr, whhp + 2 * 65536,
                                                     nullptr, pool, b0, Bc);
    }
  }

  head_kernel<<<128, 256, 0, stream>>>(pool, w1t, w2t, b1, b2, wout, bout, waux, baux,
                                       (float*)d_out);
}

// Round 7
// 759.419 us; speedup vs baseline: 1.1987x; 1.1987x over previous
//
#include <hip/hip_runtime.h>
#include <cstdint>
#include <cstddef>

typedef _Float16 f16;
typedef _Float16 f16x8 __attribute__((ext_vector_type(8)));
typedef _Float16 f16x4 __attribute__((ext_vector_type(4)));
typedef float f32x4 __attribute__((ext_vector_type(4)));

#define DEVI __device__ __forceinline__

// ---------------- problem sizes ----------------
constexpr int T_ = 256;
constexpr int BATCH = 512;
constexpr int M_ = BATCH * T_;   // 131072 tokens
constexpr int KE_ = 320;         // layer-1 K (300 padded to 320)
constexpr int K2_ = 256;         // layer-2 K

// ---------------- ws layout (bytes, 16B aligned) ----------------
constexpr size_t OFF_EMB16 = 0;                                     // [10000][320] f16
constexpr size_t OFF_WIH1  = OFF_EMB16 + (size_t)10000 * KE_ * 2;   // [1024][320] f16 (tile-permuted)
constexpr size_t OFF_WIH2  = OFF_WIH1 + (size_t)1024 * KE_ * 2;     // [1024][256] f16
constexpr size_t OFF_WHH   = OFF_WIH2 + (size_t)1024 * K2_ * 2;     // [4 ld][8w][64lane][16frag][8] f16
constexpr size_t OFF_B1    = OFF_WHH + (size_t)4 * 65536 * 2;       // [1024] f32 permuted bias
constexpr size_t OFF_B2    = OFF_B1 + 4096;                         // [1024] f32
constexpr size_t OFF_W1T   = OFF_B2 + 4096;                         // [512][512] f32 (transposed)
constexpr size_t OFF_W2T   = OFF_W1T + (size_t)512 * 512 * 4;
constexpr size_t OFF_POOL  = OFF_W2T + (size_t)512 * 512 * 4;       // [512][512] f32 (avg|max)
constexpr size_t OFF_XG1   = OFF_POOL + (size_t)512 * 512 * 4;      // [10240][1024] f16 token table (21MB)
constexpr size_t OFF_H1    = OFF_XG1 + (size_t)10240 * 1024 * 2;    // [131072][256] f16 (67MB)
constexpr size_t OFF_XG2   = OFF_H1 + (size_t)M_ * 256 * 2;         // [M_/G][1024] f16 chunk
constexpr size_t XG2_FULL  = (size_t)M_ * 1024 * 2;                 // 268MB full

DEVI void gload_lds16(const void* g, void* l) {
  __builtin_amdgcn_global_load_lds((const __attribute__((address_space(1))) void*)g,
                                   (__attribute__((address_space(3))) void*)l, 16, 0, 0);
}
DEVI float sigm(float x)  { return __builtin_amdgcn_rcpf(1.f + __expf(-x)); }
DEVI float tanh_(float x) { return 1.f - 2.f * __builtin_amdgcn_rcpf(1.f + __expf(2.f * x)); }

// xg col layout: col = dir*512 + unit*4 + gate   (gate contiguous, unit next)
// GEMM N-tile nt = dir*4 + ug; within tile r = wn*64 + j*16 + c0 -> gate=j, unit=ug*32+wn*16+c0
// B-perm row p = nt*128 + r -> orig W row = gate*128 + unit (per dir)
DEVI int borow(int p) {
  int r = p & 127;
  int ug = (p >> 7) & 3;
  int wn = r >> 6, j = (r >> 4) & 3, c0 = r & 15;
  return j * 128 + ug * 32 + wn * 16 + c0;
}

// ---------------- prep: fp16 conversion, permutation, fragment pre-arrangement ----------------
__global__ void prep_kernel(
    const float* __restrict__ emb,
    const float* __restrict__ wih1f, const float* __restrict__ whh1f,
    const float* __restrict__ bih1f, const float* __restrict__ bhh1f,
    const float* __restrict__ wih1b, const float* __restrict__ whh1b,
    const float* __restrict__ bih1b, const float* __restrict__ bhh1b,
    const float* __restrict__ wih2f, const float* __restrict__ whh2f,
    const float* __restrict__ bih2f, const float* __restrict__ bhh2f,
    const float* __restrict__ wih2b, const float* __restrict__ whh2b,
    const float* __restrict__ bih2b, const float* __restrict__ bhh2b,
    const float* __restrict__ w1, const float* __restrict__ w2,
    char* __restrict__ ws)
{
  f16* emb16   = (f16*)(ws + OFF_EMB16);
  f16* wih1p   = (f16*)(ws + OFF_WIH1);
  f16* wih2p   = (f16*)(ws + OFF_WIH2);
  f16* whhp    = (f16*)(ws + OFF_WHH);
  float* b1p   = (float*)(ws + OFF_B1);
  float* b2p   = (float*)(ws + OFF_B2);
  float* w1t   = (float*)(ws + OFF_W1T);
  float* w2t   = (float*)(ws + OFF_W2T);
  const int64_t stride = (int64_t)gridDim.x * blockDim.x;
  const int64_t t0 = (int64_t)blockIdx.x * blockDim.x + threadIdx.x;

  for (int64_t i = t0; i < (int64_t)10000 * 320; i += stride) {
    int r = (int)(i / 320), c = (int)(i % 320);
    emb16[i] = (c < 300) ? (f16)emb[r * 300 + c] : (f16)0.f;
  }
  for (int64_t i = t0; i < 1024 * 320; i += stride) {
    int p = (int)(i / 320), k = (int)(i % 320);
    int dir = p >> 9; int orig = borow(p & 511);
    const float* src = dir ? wih1b : wih1f;
    wih1p[i] = (k < 300) ? (f16)src[orig * 300 + k] : (f16)0.f;
  }
  for (int64_t i = t0; i < 1024 * 256; i += stride) {
    int p = (int)(i / 256), k = (int)(i % 256);
    int dir = p >> 9; int orig = borow(p & 511);
    const float* src = dir ? wih2b : wih2f;
    wih2p[i] = (f16)src[orig * 256 + k];
  }
  // W_hh recur B-frags: [(ld*8 + w)*64 + lane][frag f=g*4+kk][e]
  //   N-row = g*128 + w*16 + (lane&15);  k = kk*32 + (lane>>4)*8 + e
  for (int64_t i = t0; i < (int64_t)4 * 65536; i += stride) {
    int ld = (int)(i >> 16);              // layer*2 + dir
    int rem = (int)(i & 65535);
    int rec = rem >> 7;                    // w*64 + lane
    int w_ = rec >> 6, lane_ = rec & 63;
    int fe = rem & 127; int f_ = fe >> 3, e_ = fe & 7;
    int g_ = f_ >> 2, kk_ = f_ & 3;
    int n = g_ * 128 + w_ * 16 + (lane_ & 15);
    int k = kk_ * 32 + (lane_ >> 4) * 8 + e_;
    const float* src = (ld == 0) ? whh1f : (ld == 1) ? whh1b : (ld == 2) ? whh2f : whh2b;
    whhp[i] = (f16)src[n * 128 + k];
  }
  for (int64_t i = t0; i < 1024; i += stride) {
    int dir = (int)(i >> 9); int orig = borow((int)(i & 511));
    b1p[i] = dir ? (bih1b[orig] + bhh1b[orig]) : (bih1f[orig] + bhh1f[orig]);
    b2p[i] = dir ? (bih2b[orig] + bhh2b[orig]) : (bih2f[orig] + bhh2f[orig]);
  }
  for (int64_t i = t0; i < 512 * 512; i += stride) {
    int k = (int)(i >> 9), j = (int)(i & 511);
    w1t[i] = w1[j * 512 + k];
    w2t[i] = w2[j * 512 + k];
  }
}

// ---------------- input-gate GEMM: packed-layout xg, double-buffered LDS ----------------
// A rows linear (chunk-local / table rows). 128x128 tile, BK=64, 4 waves.
template<int KT>
__global__ __launch_bounds__(256, 2) void gemm_xg(
    const f16* __restrict__ Asrc, const f16* __restrict__ Bw,
    const float* __restrict__ bias, f16* __restrict__ xg)
{
  __shared__ __align__(16) f16 lA[2][8192];
  __shared__ __align__(16) f16 lB[2][8192];
  const int tid = threadIdx.x;
  const int w = tid >> 6, lane = tid & 63;
  const int mt = blockIdx.x >> 3, nt = blockIdx.x & 7;
  const int wm = w & 1, wn = w >> 1;
  const int l3 = lane >> 3, l7 = lane & 7;
  const int c0 = lane & 15, kg = lane >> 4;
  const int swz = l7 ^ l3;

  const f16* asrc[4];
  const f16* bsrc[4];
#pragma unroll
  for (int c = 0; c < 4; ++c) {
    int r = c * 32 + w * 8 + l3;
    asrc[c] = Asrc + (size_t)(mt * 128 + r) * (KT * 64) + swz * 8;
    bsrc[c] = Bw + (size_t)(nt * 128 + r) * (KT * 64) + swz * 8;
  }
  auto stage = [&](int kk, int d) {
#pragma unroll
    for (int c = 0; c < 4; ++c)
      gload_lds16(asrc[c] + kk * 64, &lA[d][(c * 256 + w * 64) * 8]);
#pragma unroll
    for (int c = 0; c < 4; ++c)
      gload_lds16(bsrc[c] + kk * 64, &lB[d][(c * 256 + w * 64) * 8]);
  };

  f32x4 acc[4][4] = {};
  stage(0, 0);
  for (int kk = 0; kk < KT; ++kk) {
    const int d = kk & 1;
    if (kk + 1 < KT) {
      stage(kk + 1, d ^ 1);
      asm volatile("s_waitcnt vmcnt(8)" ::: "memory");   // current tile landed, next in flight
    } else {
      asm volatile("s_waitcnt vmcnt(0)" ::: "memory");
    }
    __builtin_amdgcn_s_barrier();

    f16x8 af[2][4], bf[2][4];
#pragma unroll
    for (int s = 0; s < 2; ++s)
#pragma unroll
      for (int i = 0; i < 4; ++i) {
        int ra = wm * 64 + i * 16 + c0;
        int rb = wn * 64 + i * 16 + c0;
        int u = (s * 4 + kg) ^ l7;
        af[s][i] = *(const f16x8*)&lA[d][ra * 64 + u * 8];
        bf[s][i] = *(const f16x8*)&lB[d][rb * 64 + u * 8];
      }
#pragma unroll
    for (int s = 0; s < 2; ++s)
#pragma unroll
      for (int i = 0; i < 4; ++i)
#pragma unroll
        for (int j = 0; j < 4; ++j)
          acc[i][j] = __builtin_amdgcn_mfma_f32_16x16x32_f16(af[s][i], bf[s][j], acc[i][j], 0, 0, 0);
    asm volatile("s_waitcnt lgkmcnt(0)" ::: "memory");
    __builtin_amdgcn_s_barrier();
  }

  const int dir = nt >> 2, ug = nt & 3;
  const int unit = ug * 32 + wn * 16 + c0;
  float bj[4];
#pragma unroll
  for (int j = 0; j < 4; ++j) bj[j] = bias[nt * 128 + wn * 64 + j * 16 + c0];
#pragma unroll
  for (int i = 0; i < 4; ++i)
#pragma unroll
    for (int r = 0; r < 4; ++r) {
      int m = mt * 128 + wm * 64 + i * 16 + kg * 4 + r;
      f16x4 v = { (f16)(acc[i][0][r] + bj[0]), (f16)(acc[i][1][r] + bj[1]),
                  (f16)(acc[i][2][r] + bj[2]), (f16)(acc[i][3][r] + bj[3]) };
      *(f16x4*)&xg[(size_t)m * 1024 + dir * 512 + unit * 4] = v;
    }
}

// ---------------- LSTM recurrence v6: 256-block grids, q-outer MFMA (no dependent stalls) ----------
// block = (dir, ROWS-batch group); wave sp owns units [sp*32, sp*32+32) as 2 sub-slices.
// ROWS in {1,2,4}: rows live at MFMA M-rows j*4; lanes kg>=ROWS are clamped+predicated off.
// L1 (!IS_L2): xg = token table [10240][1024], gathered by token id (LLC-resident).
template<int IS_L2, int ROWS>
__global__ __launch_bounds__(256, 2) void recur_kernel(
    const f16* __restrict__ xg, const int* __restrict__ xtok,
    const f16* __restrict__ whh2, f16* __restrict__ h1,
    float* __restrict__ pool, int b0, int nblk)
{
  const int tid = threadIdx.x;
  const int sp = tid >> 6, lane = tid & 63;
  const int dir = blockIdx.x / nblk, ci = blockIdx.x % nblk;
  const int c0 = lane & 15, kg = lane >> 4;
  const int kgc = (kg < ROWS) ? kg : (ROWS - 1);       // clamped (OOB-safe addressing)
  const bool wr = (kg < ROWS);                          // store predicate

  __shared__ __align__(16) f16 hbuf[2][4][144];

  f16x8 Wf[2][16];                                   // 128 VGPR of W_hh B-frags
#pragma unroll
  for (int s = 0; s < 2; ++s) {
    const f16x8* wp = (const f16x8*)(whh2 + (size_t)dir * 65536 +
                                     (size_t)((sp * 2 + s) * 64 + lane) * 128);
#pragma unroll
    for (int f = 0; f < 16; ++f) Wf[s][f] = wp[f];
  }
  for (int i = tid; i < 2 * 4 * 144; i += 256) (&hbuf[0][0][0])[i] = (f16)0.f;
  __syncthreads();

  const int u0 = sp * 32 + c0, u1 = u0 + 16;
  const int brow = ci * ROWS + kgc;                  // chunk-local batch row (clamped)
  const int gb = b0 + brow;                          // global batch row
  const f16* xgu0 = xg + dir * 512 + u0 * 4;
  const f16* xgu1 = xg + dir * 512 + u1 * 4;
  const int* xr = nullptr;
  if constexpr (!IS_L2) xr = xtok + (size_t)gb * 256;

  auto tAt = [&](int step) { int s = step < 256 ? step : 255; return dir ? 255 - s : s; };

  float cst[2] = {0.f, 0.f}, psum[2] = {0.f, 0.f}, pmax[2] = {-1e30f, -1e30f};

  f16x4 xa[2], xb[2];
  int tok1 = 0;
  if constexpr (!IS_L2) {
    const int tok0 = xr[tAt(0)];
    xa[0] = *(const f16x4*)(xgu0 + (size_t)tok0 * 1024);
    xa[1] = *(const f16x4*)(xgu1 + (size_t)tok0 * 1024);
    tok1 = xr[tAt(1)];
  } else {
    const size_t m0 = ((size_t)brow * 256 + tAt(0)) * 1024;
    xa[0] = *(const f16x4*)(xgu0 + m0);
    xa[1] = *(const f16x4*)(xgu1 + m0);
  }

  auto body = [&](int step, int p, f16x4* cur, f16x4* nxt) {
    const int t = tAt(step);
    if constexpr (!IS_L2) {
      const size_t mn = (size_t)tok1 * 1024;          // token loaded last iter
      nxt[0] = *(const f16x4*)(xgu0 + mn);
      nxt[1] = *(const f16x4*)(xgu1 + mn);
      tok1 = xr[tAt(step + 2)];                       // token for step+2
    } else {
      const size_t mn = ((size_t)brow * 256 + tAt(step + 1)) * 1024;
      nxt[0] = *(const f16x4*)(xgu0 + mn);
      nxt[1] = *(const f16x4*)(xgu1 + mn);
    }

    f16x8 a[4];
#pragma unroll
    for (int q = 0; q < 4; ++q)
      a[q] = *(const f16x8*)&hbuf[p][c0 >> 2][q * 32 + kg * 8];

    // q OUTERMOST: 8 independent MFMAs between dependent reuses of each acc
    // (same per-acc accumulation order q=0..3 -> bit-identical results)
    f32x4 acc[2][4] = {};
    __builtin_amdgcn_s_setprio(1);
#pragma unroll
    for (int q = 0; q < 4; ++q)
#pragma unroll
      for (int s = 0; s < 2; ++s)
#pragma unroll
        for (int g = 0; g < 4; ++g)
          acc[s][g] = __builtin_amdgcn_mfma_f32_16x16x32_f16(a[q], Wf[s][g * 4 + q], acc[s][g], 0, 0, 0);
    __builtin_amdgcn_s_setprio(0);

#pragma unroll
    for (int s = 0; s < 2; ++s) {
      const float gi = acc[s][0][0] + (float)cur[s][0];
      const float gf = acc[s][1][0] + (float)cur[s][1];
      const float gG = acc[s][2][0] + (float)cur[s][2];
      const float go = acc[s][3][0] + (float)cur[s][3];
      const float si = sigm(gi), sf = sigm(gf), so = sigm(go);
      const float cn = sf * cst[s] + si * tanh_(gG);
      cst[s] = cn;
      const float hv = so * tanh_(cn);
      if (wr) {
        hbuf[p ^ 1][kg][s ? u1 : u0] = (f16)hv;
        if constexpr (!IS_L2)
          h1[((size_t)gb * 256 + t) * 256 + dir * 128 + (s ? u1 : u0)] = (f16)hv;
      }
      if constexpr (IS_L2) {
        psum[s] += hv;
        pmax[s] = fmaxf(pmax[s], hv);
      }
    }
    asm volatile("s_waitcnt lgkmcnt(0)" ::: "memory"); // hbuf reads+writes done
    __builtin_amdgcn_s_barrier();                      // single barrier per step
  };

#pragma unroll 1
  for (int s2 = 0; s2 < 128; ++s2) {                   // static reg double-buffer
    body(2 * s2, 0, xa, xb);
    body(2 * s2 + 1, 1, xb, xa);
  }

  if constexpr (IS_L2) {
    if (wr) {
      pool[(size_t)gb * 512 + dir * 128 + u0] = psum[0] * (1.f / 256.f);
      pool[(size_t)gb * 512 + dir * 128 + u1] = psum[1] * (1.f / 256.f);
      pool[(size_t)gb * 512 + 256 + dir * 128 + u0] = pmax[0];
      pool[(size_t)gb * 512 + 256 + dir * 128 + u1] = pmax[1];
    }
  }
}

// ---------------- head: dense(512x512)x2 + residual + out/aux projections ----------------
__global__ __launch_bounds__(256) void head_kernel(
    const float* __restrict__ pool,
    const float* __restrict__ w1t, const float* __restrict__ w2t,
    const float* __restrict__ b1, const float* __restrict__ b2,
    const float* __restrict__ wout, const float* __restrict__ bout,
    const float* __restrict__ waux, const float* __restrict__ baux,
    float* __restrict__ out)
{
  __shared__ float hc[4][512];
  __shared__ float hid[4][512];
  const int tid = threadIdx.x;
  const int rb = blockIdx.x * 4;
  for (int i = tid; i < 2048; i += 256) hc[i >> 9][i & 511] = pool[(size_t)rb * 512 + i];
  __syncthreads();

  float acc1[2][4] = {}, acc2[2][4] = {};
  for (int k = 0; k < 512; ++k) {
    float w1a = w1t[k * 512 + tid], w1b = w1t[k * 512 + tid + 256];
    float w2a = w2t[k * 512 + tid], w2b = w2t[k * 512 + tid + 256];
#pragma unroll
    for (int r = 0; r < 4; ++r) {
      float h = hc[r][k];
      acc1[0][r] += w1a * h; acc1[1][r] += w1b * h;
      acc2[0][r] += w2a * h; acc2[1][r] += w2b * h;
    }
  }
#pragma unroll
  for (int r = 0; r < 4; ++r) {
    hid[r][tid] = fmaxf(acc1[0][r] + b1[tid], 0.f) + hc[r][tid] + fmaxf(acc2[0][r] + b2[tid], 0.f);
    hid[r][tid + 256] = fmaxf(acc1[1][r] + b1[tid + 256], 0.f) + hc[r][tid + 256]
                      + fmaxf(acc2[1][r] + b2[tid + 256], 0.f);
  }
  __syncthreads();

  const int wv = tid >> 6, lane = tid & 63;
  for (int o = 0; o < 7; ++o) {
    const float* wrow = (o == 0) ? wout : (waux + (size_t)(o - 1) * 512);
    float s = 0.f;
#pragma unroll
    for (int m = 0; m < 8; ++m) s += hid[wv][lane + 64 * m] * wrow[lane + 64 * m];
#pragma unroll
    for (int off = 32; off >= 1; off >>= 1) s += __shfl_xor(s, off, 64);
    if (lane == 0) out[(size_t)(rb + wv) * 7 + o] = s + ((o == 0) ? bout[0] : baux[o - 1]);
  }
}

// ---------------- launcher ----------------
extern "C" void kernel_launch(void* const* d_in, const int* in_sizes, int n_in,
                              void* d_out, int out_size, void* d_ws, size_t ws_size,
                              hipStream_t stream) {
  const int*   x     = (const int*)d_in[0];
  const float* emb   = (const float*)d_in[1];
  const float* wih1f = (const float*)d_in[2];
  const float* whh1f = (const float*)d_in[3];
  const float* bih1f = (const float*)d_in[4];
  const float* bhh1f = (const float*)d_in[5];
  const float* wih1b = (const float*)d_in[6];
  const float* whh1b = (const float*)d_in[7];
  const float* bih1b = (const float*)d_in[8];
  const float* bhh1b = (const float*)d_in[9];
  const float* wih2f = (const float*)d_in[10];
  const float* whh2f = (const float*)d_in[11];
  const float* bih2f = (const float*)d_in[12];
  const float* bhh2f = (const float*)d_in[13];
  const float* wih2b = (const float*)d_in[14];
  const float* whh2b = (const float*)d_in[15];
  const float* bih2b = (const float*)d_in[16];
  const float* bhh2b = (const float*)d_in[17];
  const float* w1    = (const float*)d_in[18];
  const float* b1    = (const float*)d_in[19];
  const float* w2    = (const float*)d_in[20];
  const float* b2    = (const float*)d_in[21];
  const float* wout  = (const float*)d_in[22];
  const float* bout  = (const float*)d_in[23];
  const float* waux  = (const float*)d_in[24];
  const float* baux  = (const float*)d_in[25];

  char* ws = (char*)d_ws;
  f16* emb16 = (f16*)(ws + OFF_EMB16);
  f16* wih1p = (f16*)(ws + OFF_WIH1);
  f16* wih2p = (f16*)(ws + OFF_WIH2);
  f16* whhp  = (f16*)(ws + OFF_WHH);
  float* b1p = (float*)(ws + OFF_B1);
  float* b2p = (float*)(ws + OFF_B2);
  float* w1t = (float*)(ws + OFF_W1T);
  float* w2t = (float*)(ws + OFF_W2T);
  float* pool = (float*)(ws + OFF_POOL);
  f16* xg1t  = (f16*)(ws + OFF_XG1);
  f16* h1f   = (f16*)(ws + OFF_H1);
  f16* xg2c  = (f16*)(ws + OFF_XG2);

  // chunk factor G for the layer-2 xg buffer only (pure function of ws_size)
  int G = 1;
  while (G < 32 && OFF_XG2 + XG2_FULL / (size_t)G > ws_size) G <<= 1;
  const int Bc = BATCH / G;

  prep_kernel<<<4096, 256, 0, stream>>>(emb,
      wih1f, whh1f, bih1f, bhh1f, wih1b, whh1b, bih1b, bhh1b,
      wih2f, whh2f, bih2f, bhh2f, wih2b, whh2b, bih2b, bhh2b,
      w1, w2, ws);

  // layer-1 gate table over the 10000-token vocabulary (80 M-tiles of 128)
  gemm_xg<5><<<80 * 8, 256, 0, stream>>>(emb16, wih1p, b1p, xg1t);

  // layer-1 recurrence: ROWS=4 -> exactly 256 blocks (minimal issue, full chip)
  recur_kernel<0, 4><<<2 * 128, 256, 0, stream>>>(xg1t, x, whhp, h1f, nullptr, 0, 128);

  // layer-2: chunked input GEMM + recurrence; ROWS chosen so grid == 256 where possible
  for (int g = 0; g < G; ++g) {
    const int b0 = g * Bc;
    gemm_xg<4><<<(Bc * 2) * 8, 256, 0, stream>>>(h1f + (size_t)b0 * 65536, wih2p, b2p, xg2c);
    if (Bc >= 512) {
      recur_kernel<1, 4><<<2 * (Bc / 4), 256, 0, stream>>>(xg2c, nullptr, whhp + 2 * 65536,
                                                           nullptr, pool, b0, Bc / 4);
    } else if (Bc >= 256) {
      recur_kernel<1, 2><<<2 * (Bc / 2), 256, 0, stream>>>(xg2c, nullptr, whhp + 2 * 65536,
                                                           nullptr, pool, b0, Bc / 2);
    } else {
      recur_kernel<1, 1><<<2 * Bc, 256, 0, stream>>>(xg2c, nullptr, whhp + 2 * 65536,
                                                     nullptr, pool, b0, Bc);
    }
  }

  head_kernel<<<128, 256, 0, stream>>>(pool, w1t, w2t, b1, b2, wout, bout, waux, baux,
                                       (float*)d_out);
}

// Round 8
// 730.471 us; speedup vs baseline: 1.2462x; 1.0396x over previous
//
#include <hip/hip_runtime.h>
#include <cstdint>
#include <cstddef>

typedef _Float16 f16;
typedef _Float16 f16x8 __attribute__((ext_vector_type(8)));
typedef _Float16 f16x4 __attribute__((ext_vector_type(4)));
typedef float f32x4 __attribute__((ext_vector_type(4)));

#define DEVI __device__ __forceinline__

// ---------------- problem sizes ----------------
constexpr int T_ = 256;
constexpr int BATCH = 512;
constexpr int M_ = BATCH * T_;   // 131072 tokens
constexpr int KE_ = 320;         // layer-1 K (300 padded to 320)
constexpr int K2_ = 256;         // layer-2 K

constexpr float L2E  = 1.4426950408889634f;   // log2(e), folded into i,f,o gate rows
constexpr float L2E2 = 2.8853900817779268f;   // 2*log2(e), folded into g gate rows

// ---------------- ws layout (bytes, 16B aligned) ----------------
constexpr size_t OFF_EMB16 = 0;                                     // [10000][320] f16
constexpr size_t OFF_WIH1  = OFF_EMB16 + (size_t)10000 * KE_ * 2;   // [1024][320] f16 (tile-permuted, gate-scaled)
constexpr size_t OFF_WIH2  = OFF_WIH1 + (size_t)1024 * KE_ * 2;     // [1024][256] f16
constexpr size_t OFF_WHH   = OFF_WIH2 + (size_t)1024 * K2_ * 2;     // [4 ld][8w][64lane][16frag][8] f16
constexpr size_t OFF_B1    = OFF_WHH + (size_t)4 * 65536 * 2;       // [1024] f32 permuted+scaled bias
constexpr size_t OFF_B2    = OFF_B1 + 4096;                         // [1024] f32
constexpr size_t OFF_W1T   = OFF_B2 + 4096;                         // [512][512] f32 (transposed)
constexpr size_t OFF_W2T   = OFF_W1T + (size_t)512 * 512 * 4;
constexpr size_t OFF_POOL  = OFF_W2T + (size_t)512 * 512 * 4;       // [512][512] f32 (avg|max)
constexpr size_t OFF_XG1   = OFF_POOL + (size_t)512 * 512 * 4;      // [10240][1024] f16 token table (21MB)
constexpr size_t OFF_H1    = OFF_XG1 + (size_t)10240 * 1024 * 2;    // [131072][256] f16 (67MB)
constexpr size_t OFF_XG2   = OFF_H1 + (size_t)M_ * 256 * 2;         // [M_/G][1024] f16 chunk
constexpr size_t XG2_FULL  = (size_t)M_ * 1024 * 2;                 // 268MB full

DEVI void gload_lds16(const void* g, void* l) {
  __builtin_amdgcn_global_load_lds((const __attribute__((address_space(1))) void*)g,
                                   (__attribute__((address_space(3))) void*)l, 16, 0, 0);
}
DEVI float exp2_(float x) { float r; asm("v_exp_f32 %0, %1" : "=v"(r) : "v"(x)); return r; }
DEVI float rcp_(float x)  { return __builtin_amdgcn_rcpf(x); }

// xg col layout: col = dir*512 + unit*4 + gate   (gate contiguous, unit next)
// GEMM N-tile nt = dir*4 + ug; within tile r = wn*64 + j*16 + c0 -> gate=j, unit=ug*32+wn*16+c0
// B-perm row p = nt*128 + r -> orig W row = gate*128 + unit (per dir)
DEVI int borow(int p) {
  int r = p & 127;
  int ug = (p >> 7) & 3;
  int wn = r >> 6, j = (r >> 4) & 3, c0 = r & 15;
  return j * 128 + ug * 32 + wn * 16 + c0;
}
DEVI float gscale(int gate) { return (gate == 2) ? L2E2 : L2E; }

// ---------------- prep: fp16 conversion, permutation, gate-scale folding ----------------
__global__ void prep_kernel(
    const float* __restrict__ emb,
    const float* __restrict__ wih1f, const float* __restrict__ whh1f,
    const float* __restrict__ bih1f, const float* __restrict__ bhh1f,
    const float* __restrict__ wih1b, const float* __restrict__ whh1b,
    const float* __restrict__ bih1b, const float* __restrict__ bhh1b,
    const float* __restrict__ wih2f, const float* __restrict__ whh2f,
    const float* __restrict__ bih2f, const float* __restrict__ bhh2f,
    const float* __restrict__ wih2b, const float* __restrict__ whh2b,
    const float* __restrict__ bih2b, const float* __restrict__ bhh2b,
    const float* __restrict__ w1, const float* __restrict__ w2,
    char* __restrict__ ws)
{
  f16* emb16   = (f16*)(ws + OFF_EMB16);
  f16* wih1p   = (f16*)(ws + OFF_WIH1);
  f16* wih2p   = (f16*)(ws + OFF_WIH2);
  f16* whhp    = (f16*)(ws + OFF_WHH);
  float* b1p   = (float*)(ws + OFF_B1);
  float* b2p   = (float*)(ws + OFF_B2);
  float* w1t   = (float*)(ws + OFF_W1T);
  float* w2t   = (float*)(ws + OFF_W2T);
  const int64_t stride = (int64_t)gridDim.x * blockDim.x;
  const int64_t t0 = (int64_t)blockIdx.x * blockDim.x + threadIdx.x;

  for (int64_t i = t0; i < (int64_t)10000 * 320; i += stride) {
    int r = (int)(i / 320), c = (int)(i % 320);
    emb16[i] = (c < 300) ? (f16)emb[r * 300 + c] : (f16)0.f;
  }
  for (int64_t i = t0; i < 1024 * 320; i += stride) {
    int p = (int)(i / 320), k = (int)(i % 320);
    int dir = p >> 9; int pr = p & 511; int orig = borow(pr);
    float sc = gscale((pr >> 4) & 3);
    const float* src = dir ? wih1b : wih1f;
    wih1p[i] = (k < 300) ? (f16)(src[orig * 300 + k] * sc) : (f16)0.f;
  }
  for (int64_t i = t0; i < 1024 * 256; i += stride) {
    int p = (int)(i / 256), k = (int)(i % 256);
    int dir = p >> 9; int pr = p & 511; int orig = borow(pr);
    float sc = gscale((pr >> 4) & 3);
    const float* src = dir ? wih2b : wih2f;
    wih2p[i] = (f16)(src[orig * 256 + k] * sc);
  }
  // W_hh recur B-frags: [(ld*8 + w)*64 + lane][frag f=g*4+kk][e]
  //   N-row = g*128 + w*16 + (lane&15);  k = kk*32 + (lane>>4)*8 + e
  for (int64_t i = t0; i < (int64_t)4 * 65536; i += stride) {
    int ld = (int)(i >> 16);              // layer*2 + dir
    int rem = (int)(i & 65535);
    int rec = rem >> 7;                    // w*64 + lane
    int w_ = rec >> 6, lane_ = rec & 63;
    int fe = rem & 127; int f_ = fe >> 3, e_ = fe & 7;
    int g_ = f_ >> 2, kk_ = f_ & 3;
    int n = g_ * 128 + w_ * 16 + (lane_ & 15);
    int k = kk_ * 32 + (lane_ >> 4) * 8 + e_;
    const float* src = (ld == 0) ? whh1f : (ld == 1) ? whh1b : (ld == 2) ? whh2f : whh2b;
    whhp[i] = (f16)(src[n * 128 + k] * gscale(g_));
  }
  for (int64_t i = t0; i < 1024; i += stride) {
    int dir = (int)(i >> 9); int pr = (int)(i & 511); int orig = borow(pr);
    float sc = gscale((pr >> 4) & 3);
    b1p[i] = sc * (dir ? (bih1b[orig] + bhh1b[orig]) : (bih1f[orig] + bhh1f[orig]));
    b2p[i] = sc * (dir ? (bih2b[orig] + bhh2b[orig]) : (bih2f[orig] + bhh2f[orig]));
  }
  for (int64_t i = t0; i < 512 * 512; i += stride) {
    int k = (int)(i >> 9), j = (int)(i & 511);
    w1t[i] = w1[j * 512 + k];
    w2t[i] = w2[j * 512 + k];
  }
}

// ---------------- input-gate GEMM: packed-layout xg, double-buffered LDS ----------------
// A rows linear (chunk-local / table rows). 128x128 tile, BK=64, 4 waves.
template<int KT>
__global__ __launch_bounds__(256, 2) void gemm_xg(
    const f16* __restrict__ Asrc, const f16* __restrict__ Bw,
    const float* __restrict__ bias, f16* __restrict__ xg)
{
  __shared__ __align__(16) f16 lA[2][8192];
  __shared__ __align__(16) f16 lB[2][8192];
  const int tid = threadIdx.x;
  const int w = tid >> 6, lane = tid & 63;
  const int mt = blockIdx.x >> 3, nt = blockIdx.x & 7;
  const int wm = w & 1, wn = w >> 1;
  const int l3 = lane >> 3, l7 = lane & 7;
  const int c0 = lane & 15, kg = lane >> 4;
  const int swz = l7 ^ l3;

  const f16* asrc[4];
  const f16* bsrc[4];
#pragma unroll
  for (int c = 0; c < 4; ++c) {
    int r = c * 32 + w * 8 + l3;
    asrc[c] = Asrc + (size_t)(mt * 128 + r) * (KT * 64) + swz * 8;
    bsrc[c] = Bw + (size_t)(nt * 128 + r) * (KT * 64) + swz * 8;
  }
  auto stage = [&](int kk, int d) {
#pragma unroll
    for (int c = 0; c < 4; ++c)
      gload_lds16(asrc[c] + kk * 64, &lA[d][(c * 256 + w * 64) * 8]);
#pragma unroll
    for (int c = 0; c < 4; ++c)
      gload_lds16(bsrc[c] + kk * 64, &lB[d][(c * 256 + w * 64) * 8]);
  };

  f32x4 acc[4][4] = {};
  stage(0, 0);
  for (int kk = 0; kk < KT; ++kk) {
    const int d = kk & 1;
    if (kk + 1 < KT) {
      stage(kk + 1, d ^ 1);
      asm volatile("s_waitcnt vmcnt(8)" ::: "memory");   // current tile landed, next in flight
    } else {
      asm volatile("s_waitcnt vmcnt(0)" ::: "memory");
    }
    __builtin_amdgcn_s_barrier();

    f16x8 af[2][4], bf[2][4];
#pragma unroll
    for (int s = 0; s < 2; ++s)
#pragma unroll
      for (int i = 0; i < 4; ++i) {
        int ra = wm * 64 + i * 16 + c0;
        int rb = wn * 64 + i * 16 + c0;
        int u = (s * 4 + kg) ^ l7;
        af[s][i] = *(const f16x8*)&lA[d][ra * 64 + u * 8];
        bf[s][i] = *(const f16x8*)&lB[d][rb * 64 + u * 8];
      }
#pragma unroll
    for (int s = 0; s < 2; ++s)
#pragma unroll
      for (int i = 0; i < 4; ++i)
#pragma unroll
        for (int j = 0; j < 4; ++j)
          acc[i][j] = __builtin_amdgcn_mfma_f32_16x16x32_f16(af[s][i], bf[s][j], acc[i][j], 0, 0, 0);
    asm volatile("s_waitcnt lgkmcnt(0)" ::: "memory");
    __builtin_amdgcn_s_barrier();
  }

  const int dir = nt >> 2, ug = nt & 3;
  const int unit = ug * 32 + wn * 16 + c0;
  float bj[4];
#pragma unroll
  for (int j = 0; j < 4; ++j) bj[j] = bias[nt * 128 + wn * 64 + j * 16 + c0];
#pragma unroll
  for (int i = 0; i < 4; ++i)
#pragma unroll
    for (int r = 0; r < 4; ++r) {
      int m = mt * 128 + wm * 64 + i * 16 + kg * 4 + r;
      f16x4 v = { (f16)(acc[i][0][r] + bj[0]), (f16)(acc[i][1][r] + bj[1]),
                  (f16)(acc[i][2][r] + bj[2]), (f16)(acc[i][3][r] + bj[3]) };
      *(f16x4*)&xg[(size_t)m * 1024 + dir * 512 + unit * 4] = v;
    }
}

// ---------------- LSTM recurrence v7: r5-proven body (q-inner, no setprio) + exp2 gates -------
// block = (dir, ROWS-batch group); wave sp owns units [sp*32, sp*32+32) as 2 sub-slices.
// ROWS in {1,2,4}: rows live at MFMA M-rows j*4; lanes kg>=ROWS are clamped+predicated off.
// L1 (!IS_L2): xg = token table [10240][1024], gathered by token id (LLC-resident).
// Gate pre-activations arrive pre-scaled by log2e (i,f,o) / 2log2e (g) -> exp2 directly.
template<int IS_L2, int ROWS>
__global__ __launch_bounds__(256, 2) void recur_kernel(
    const f16* __restrict__ xg, const int* __restrict__ xtok,
    const f16* __restrict__ whh2, f16* __restrict__ h1,
    float* __restrict__ pool, int b0, int nblk)
{
  const int tid = threadIdx.x;
  const int sp = tid >> 6, lane = tid & 63;
  const int dir = blockIdx.x / nblk, ci = blockIdx.x % nblk;
  const int c0 = lane & 15, kg = lane >> 4;
  const int kgc = (kg < ROWS) ? kg : (ROWS - 1);       // clamped (OOB-safe addressing)
  const bool wr = (kg < ROWS);                          // store predicate

  __shared__ __align__(16) f16 hbuf[2][4][144];

  f16x8 Wf[2][16];                                   // 128 VGPR of W_hh B-frags
#pragma unroll
  for (int s = 0; s < 2; ++s) {
    const f16x8* wp = (const f16x8*)(whh2 + (size_t)dir * 65536 +
                                     (size_t)((sp * 2 + s) * 64 + lane) * 128);
#pragma unroll
    for (int f = 0; f < 16; ++f) Wf[s][f] = wp[f];
  }
  for (int i = tid; i < 2 * 4 * 144; i += 256) (&hbuf[0][0][0])[i] = (f16)0.f;
  __syncthreads();

  const int u0 = sp * 32 + c0, u1 = u0 + 16;
  const int brow = ci * ROWS + kgc;                  // chunk-local batch row (clamped)
  const int gb = b0 + brow;                          // global batch row
  const f16* xgu0 = xg + dir * 512 + u0 * 4;
  const f16* xgu1 = xg + dir * 512 + u1 * 4;
  const int* xr = nullptr;
  if constexpr (!IS_L2) xr = xtok + (size_t)gb * 256;

  auto tAt = [&](int step) { int s = step < 256 ? step : 255; return dir ? 255 - s : s; };

  float cst[2] = {0.f, 0.f}, psum[2] = {0.f, 0.f}, pmax[2] = {-1e30f, -1e30f};

  f16x4 xa[2], xb[2];
  int tok1 = 0;
  if constexpr (!IS_L2) {
    const int tok0 = xr[tAt(0)];
    xa[0] = *(const f16x4*)(xgu0 + (size_t)tok0 * 1024);
    xa[1] = *(const f16x4*)(xgu1 + (size_t)tok0 * 1024);
    tok1 = xr[tAt(1)];
  } else {
    const size_t m0 = ((size_t)brow * 256 + tAt(0)) * 1024;
    xa[0] = *(const f16x4*)(xgu0 + m0);
    xa[1] = *(const f16x4*)(xgu1 + m0);
  }

  auto body = [&](int step, int p, f16x4* cur, f16x4* nxt) {
    const int t = tAt(step);
    if constexpr (!IS_L2) {
      const size_t mn = (size_t)tok1 * 1024;          // token loaded last iter
      nxt[0] = *(const f16x4*)(xgu0 + mn);
      nxt[1] = *(const f16x4*)(xgu1 + mn);
      tok1 = xr[tAt(step + 2)];                       // token for step+2
    } else {
      const size_t mn = ((size_t)brow * 256 + tAt(step + 1)) * 1024;
      nxt[0] = *(const f16x4*)(xgu0 + mn);
      nxt[1] = *(const f16x4*)(xgu1 + mn);
    }

    f16x8 a[4];
#pragma unroll
    for (int q = 0; q < 4; ++q)
      a[q] = *(const f16x8*)&hbuf[p][c0 >> 2][q * 32 + kg * 8];

    // r5-proven ordering: s,g outer, q inner (per-acc chain of 4) — measured fastest
    f32x4 acc[2][4] = {};
#pragma unroll
    for (int s = 0; s < 2; ++s)
#pragma unroll
      for (int g = 0; g < 4; ++g)
#pragma unroll
        for (int q = 0; q < 4; ++q)
          acc[s][g] = __builtin_amdgcn_mfma_f32_16x16x32_f16(a[q], Wf[s][g * 4 + q], acc[s][g], 0, 0, 0);

#pragma unroll
    for (int s = 0; s < 2; ++s) {
      const float gi = acc[s][0][0] + (float)cur[s][0];   // pre-scaled by log2e
      const float gf = acc[s][1][0] + (float)cur[s][1];
      const float gG = acc[s][2][0] + (float)cur[s][2];   // pre-scaled by 2log2e
      const float go = acc[s][3][0] + (float)cur[s][3];
      const float si = rcp_(1.f + exp2_(-gi));
      const float sf = rcp_(1.f + exp2_(-gf));
      const float so = rcp_(1.f + exp2_(-go));
      const float tg = 1.f - 2.f * rcp_(1.f + exp2_(gG));
      const float cn = sf * cst[s] + si * tg;
      cst[s] = cn;
      const float th = 1.f - 2.f * rcp_(1.f + exp2_(cn * L2E2));
      const float hv = so * th;
      if (wr) {
        hbuf[p ^ 1][kg][s ? u1 : u0] = (f16)hv;
        if constexpr (!IS_L2)
          h1[((size_t)gb * 256 + t) * 256 + dir * 128 + (s ? u1 : u0)] = (f16)hv;
      }
      if constexpr (IS_L2) {
        psum[s] += hv;
        pmax[s] = fmaxf(pmax[s], hv);
      }
    }
    asm volatile("s_waitcnt lgkmcnt(0)" ::: "memory"); // hbuf reads+writes done
    __builtin_amdgcn_s_barrier();                      // single barrier per step
  };

#pragma unroll 1
  for (int s2 = 0; s2 < 128; ++s2) {                   // static reg double-buffer
    body(2 * s2, 0, xa, xb);
    body(2 * s2 + 1, 1, xb, xa);
  }

  if constexpr (IS_L2) {
    if (wr) {
      pool[(size_t)gb * 512 + dir * 128 + u0] = psum[0] * (1.f / 256.f);
      pool[(size_t)gb * 512 + dir * 128 + u1] = psum[1] * (1.f / 256.f);
      pool[(size_t)gb * 512 + 256 + dir * 128 + u0] = pmax[0];
      pool[(size_t)gb * 512 + 256 + dir * 128 + u1] = pmax[1];
    }
  }
}

// ---------------- head: dense(512x512)x2 + residual + out/aux projections ----------------
__global__ __launch_bounds__(256) void head_kernel(
    const float* __restrict__ pool,
    const float* __restrict__ w1t, const float* __restrict__ w2t,
    const float* __restrict__ b1, const float* __restrict__ b2,
    const float* __restrict__ wout, const float* __restrict__ bout,
    const float* __restrict__ waux, const float* __restrict__ baux,
    float* __restrict__ out)
{
  __shared__ float hc[4][512];
  __shared__ float hid[4][512];
  const int tid = threadIdx.x;
  const int rb = blockIdx.x * 4;
  for (int i = tid; i < 2048; i += 256) hc[i >> 9][i & 511] = pool[(size_t)rb * 512 + i];
  __syncthreads();

  float acc1[2][4] = {}, acc2[2][4] = {};
  for (int k = 0; k < 512; ++k) {
    float w1a = w1t[k * 512 + tid], w1b = w1t[k * 512 + tid + 256];
    float w2a = w2t[k * 512 + tid], w2b = w2t[k * 512 + tid + 256];
#pragma unroll
    for (int r = 0; r < 4; ++r) {
      float h = hc[r][k];
      acc1[0][r] += w1a * h; acc1[1][r] += w1b * h;
      acc2[0][r] += w2a * h; acc2[1][r] += w2b * h;
    }
  }
#pragma unroll
  for (int r = 0; r < 4; ++r) {
    hid[r][tid] = fmaxf(acc1[0][r] + b1[tid], 0.f) + hc[r][tid] + fmaxf(acc2[0][r] + b2[tid], 0.f);
    hid[r][tid + 256] = fmaxf(acc1[1][r] + b1[tid + 256], 0.f) + hc[r][tid + 256]
                      + fmaxf(acc2[1][r] + b2[tid + 256], 0.f);
  }
  __syncthreads();

  const int wv = tid >> 6, lane = tid & 63;
  for (int o = 0; o < 7; ++o) {
    const float* wrow = (o == 0) ? wout : (waux + (size_t)(o - 1) * 512);
    float s = 0.f;
#pragma unroll
    for (int m = 0; m < 8; ++m) s += hid[wv][lane + 64 * m] * wrow[lane + 64 * m];
#pragma unroll
    for (int off = 32; off >= 1; off >>= 1) s += __shfl_xor(s, off, 64);
    if (lane == 0) out[(size_t)(rb + wv) * 7 + o] = s + ((o == 0) ? bout[0] : baux[o - 1]);
  }
}

// ---------------- launcher ----------------
extern "C" void kernel_launch(void* const* d_in, const int* in_sizes, int n_in,
                              void* d_out, int out_size, void* d_ws, size_t ws_size,
                              hipStream_t stream) {
  const int*   x     = (const int*)d_in[0];
  const float* emb   = (const float*)d_in[1];
  const float* wih1f = (const float*)d_in[2];
  const float* whh1f = (const float*)d_in[3];
  const float* bih1f = (const float*)d_in[4];
  const float* bhh1f = (const float*)d_in[5];
  const float* wih1b = (const float*)d_in[6];
  const float* whh1b = (const float*)d_in[7];
  const float* bih1b = (const float*)d_in[8];
  const float* bhh1b = (const float*)d_in[9];
  const float* wih2f = (const float*)d_in[10];
  const float* whh2f = (const float*)d_in[11];
  const float* bih2f = (const float*)d_in[12];
  const float* bhh2f = (const float*)d_in[13];
  const float* wih2b = (const float*)d_in[14];
  const float* whh2b = (const float*)d_in[15];
  const float* bih2b = (const float*)d_in[16];
  const float* bhh2b = (const float*)d_in[17];
  const float* w1    = (const float*)d_in[18];
  const float* b1    = (const float*)d_in[19];
  const float* w2    = (const float*)d_in[20];
  const float* b2    = (const float*)d_in[21];
  const float* wout  = (const float*)d_in[22];
  const float* bout  = (const float*)d_in[23];
  const float* waux  = (const float*)d_in[24];
  const float* baux  = (const float*)d_in[25];

  char* ws = (char*)d_ws;
  f16* emb16 = (f16*)(ws + OFF_EMB16);
  f16* wih1p = (f16*)(ws + OFF_WIH1);
  f16* wih2p = (f16*)(ws + OFF_WIH2);
  f16* whhp  = (f16*)(ws + OFF_WHH);
  float* b1p = (float*)(ws + OFF_B1);
  float* b2p = (float*)(ws + OFF_B2);
  float* w1t = (float*)(ws + OFF_W1T);
  float* w2t = (float*)(ws + OFF_W2T);
  float* pool = (float*)(ws + OFF_POOL);
  f16* xg1t  = (f16*)(ws + OFF_XG1);
  f16* h1f   = (f16*)(ws + OFF_H1);
  f16* xg2c  = (f16*)(ws + OFF_XG2);

  // chunk factor G for the layer-2 xg buffer only (pure function of ws_size)
  int G = 1;
  while (G < 32 && OFF_XG2 + XG2_FULL / (size_t)G > ws_size) G <<= 1;
  const int Bc = BATCH / G;

  prep_kernel<<<4096, 256, 0, stream>>>(emb,
      wih1f, whh1f, bih1f, bhh1f, wih1b, whh1b, bih1b, bhh1b,
      wih2f, whh2f, bih2f, bhh2f, wih2b, whh2b, bih2b, bhh2b,
      w1, w2, ws);

  // layer-1 gate table over the 10000-token vocabulary (80 M-tiles of 128)
  gemm_xg<5><<<80 * 8, 256, 0, stream>>>(emb16, wih1p, b1p, xg1t);

  // layer-1 recurrence: ROWS=4 -> exactly 256 blocks (minimal issue, full chip)
  recur_kernel<0, 4><<<2 * 128, 256, 0, stream>>>(xg1t, x, whhp, h1f, nullptr, 0, 128);

  // layer-2: chunked input GEMM + recurrence; ROWS chosen so grid == 256 where possible
  for (int g = 0; g < G; ++g) {
    const int b0 = g * Bc;
    gemm_xg<4><<<(Bc * 2) * 8, 256, 0, stream>>>(h1f + (size_t)b0 * 65536, wih2p, b2p, xg2c);
    if (Bc >= 512) {
      recur_kernel<1, 4><<<2 * (Bc / 4), 256, 0, stream>>>(xg2c, nullptr, whhp + 2 * 65536,
                                                           nullptr, pool, b0, Bc / 4);
    } else if (Bc >= 256) {
      recur_kernel<1, 2><<<2 * (Bc / 2), 256, 0, stream>>>(xg2c, nullptr, whhp + 2 * 65536,
                                                           nullptr, pool, b0, Bc / 2);
    } else {
      recur_kernel<1, 1><<<2 * Bc, 256, 0, stream>>>(xg2c, nullptr, whhp + 2 * 65536,
                                                     nullptr, pool, b0, Bc);
    }
  }

  head_kernel<<<128, 256, 0, stream>>>(pool, w1t, w2t, b1, b2, wout, bout, waux, baux,
                                       (float*)d_out);
}